// Round 1
// 67.548 us; speedup vs baseline: 1.0171x; 1.0171x over previous
//
#include <hip/hip_runtime.h>
#include <hip/hip_bf16.h>

// Problem constants (from reference): batch=512, N_IN=128, N_OUT=256, K=3, G=3
// n = N_IN*N_OUT = 32768, grid has G+2K+1 = 10 knots (identical for every row),
// c_basis has G+K = 6 coeffs per j.
//
// Restructured as out = (1/128) * F (512x896) * W^T (256x896):
//   k = i*7 + t ; F[b][i*7+t] = B_t(x[b,i]) for t<6, swish(x[b,i]) for t=6
//   W[o][i*7+t] = c_spl[j]*c_basis[j][t] for t<6, c_res[j] for t=6  (j=o*128+i)

typedef short short8 __attribute__((ext_vector_type(8)));
typedef float f32x4 __attribute__((ext_vector_type(4)));

static __device__ inline unsigned short bf16_bits(float f) {
    union { __hip_bfloat16 h; unsigned short u; } cvt;
    cvt.h = __float2bfloat16(f);
    return cvt.u;
}

// ---------------------------------------------------------------------------
// Kernel 1: build features F (512x896 bf16) and weights W (256x896 bf16)
// tid <  65536           : one (b,i) -> 6 basis values + swish     -> F
// tid in [65536, 98304)  : one j=(o,i) -> 6 scaled coeffs + c_res  -> W
// ---------------------------------------------------------------------------
__global__ __launch_bounds__(256) void build_fw(
    const float* __restrict__ x,        // (512,128)
    const float* __restrict__ grid,     // (32768,10) -- all rows identical
    const float* __restrict__ c_basis,  // (32768,6)
    const float* __restrict__ c_spl,    // (32768,)
    const float* __restrict__ c_res,    // (32768,)
    unsigned short* __restrict__ F,     // (512,896) bf16 bits
    unsigned short* __restrict__ W)     // (256,896) bf16 bits
{
    const int tid = blockIdx.x * 256 + threadIdx.x;

    if (tid < 512 * 128) {
        // knot vector from grid row 0 (rows are identical by construction)
        float t[10];
#pragma unroll
        for (int m = 0; m < 10; ++m) t[m] = grid[m];

        const float xv = x[tid];            // x row-major: tid = b*128+i

        // Cox-de Boor, order 0 -> 3 (matches reference get_spline_basis)
        float b0[9];
#pragma unroll
        for (int s = 0; s < 9; ++s)
            b0[s] = (xv >= t[s] && xv < t[s + 1]) ? 1.0f : 0.0f;
        float b1[8];
#pragma unroll
        for (int s = 0; s < 8; ++s)
            b1[s] = (xv - t[s]) / (t[s + 1] - t[s]) * b0[s]
                  + (t[s + 2] - xv) / (t[s + 2] - t[s + 1]) * b0[s + 1];
        float b2[7];
#pragma unroll
        for (int s = 0; s < 7; ++s)
            b2[s] = (xv - t[s]) / (t[s + 2] - t[s]) * b1[s]
                  + (t[s + 3] - xv) / (t[s + 3] - t[s + 1]) * b1[s + 1];
        float b3[6];
#pragma unroll
        for (int s = 0; s < 6; ++s)
            b3[s] = (xv - t[s]) / (t[s + 3] - t[s]) * b2[s]
                  + (t[s + 4] - xv) / (t[s + 4] - t[s + 1]) * b2[s + 1];

        const float sw = xv / (1.0f + expf(-xv));   // swish

        // F[b*896 + i*7 + t] == F[tid*7 + t] since 896 = 128*7
        unsigned short* dst = F + tid * 7;
#pragma unroll
        for (int s = 0; s < 6; ++s) dst[s] = bf16_bits(b3[s]);
        dst[6] = bf16_bits(sw);
    } else if (tid < 512 * 128 + 32768) {
        const int j = tid - 512 * 128;      // j = o*128 + i
        // W[o*896 + i*7 + t] == W[j*7 + t]
        unsigned short* dst = W + j * 7;
        const float spl = c_spl[j];
#pragma unroll
        for (int s = 0; s < 6; ++s) dst[s] = bf16_bits(spl * c_basis[j * 6 + s]);
        dst[6] = bf16_bits(c_res[j]);
    }
}

// ---------------------------------------------------------------------------
// Kernel 2: out(512x256 f32) = (1/128) * F * W^T via mfma_f32_16x16x32_bf16
// One wave (64 threads) per 16x16 output tile; 512 tiles; K=896 = 28 steps,
// unrolled x4 for load-level parallelism. All data is L2/L3-resident.
// A-frag: lane holds A[m=lane&15][k = (lane>>4)*8 + j], 16B contiguous.
// B-frag: lane holds B[n=lane&15][k = (lane>>4)*8 + j], 16B contiguous (W o-major).
// C/D:    col = lane&15 (o), row = (lane>>4)*4 + reg (b)   [m89-verified]
// ---------------------------------------------------------------------------
__global__ __launch_bounds__(64) void kan_gemm(
    const unsigned short* __restrict__ F,   // (512,896) bf16
    const unsigned short* __restrict__ W,   // (256,896) bf16
    float* __restrict__ out)                // (512,256) f32
{
    const int bt   = blockIdx.x >> 4;   // 0..31 batch tile
    const int ot   = blockIdx.x & 15;   // 0..15 output tile
    const int lane = threadIdx.x;
    const int r    = lane & 15;
    const int q    = lane >> 4;

    const unsigned short* fp = F + (bt * 16 + r) * 896 + q * 8;
    const unsigned short* wp = W + (ot * 16 + r) * 896 + q * 8;

    f32x4 acc = {0.0f, 0.0f, 0.0f, 0.0f};

#pragma unroll
    for (int k0 = 0; k0 < 896; k0 += 128) {
        short8 a0 = *(const short8*)(fp + k0);
        short8 a1 = *(const short8*)(fp + k0 + 32);
        short8 a2 = *(const short8*)(fp + k0 + 64);
        short8 a3 = *(const short8*)(fp + k0 + 96);
        short8 w0 = *(const short8*)(wp + k0);
        short8 w1 = *(const short8*)(wp + k0 + 32);
        short8 w2 = *(const short8*)(wp + k0 + 64);
        short8 w3 = *(const short8*)(wp + k0 + 96);
        acc = __builtin_amdgcn_mfma_f32_16x16x32_bf16(a0, w0, acc, 0, 0, 0);
        acc = __builtin_amdgcn_mfma_f32_16x16x32_bf16(a1, w1, acc, 0, 0, 0);
        acc = __builtin_amdgcn_mfma_f32_16x16x32_bf16(a2, w2, acc, 0, 0, 0);
        acc = __builtin_amdgcn_mfma_f32_16x16x32_bf16(a3, w3, acc, 0, 0, 0);
    }

    const float scale = 1.0f / 128.0f;
    const int orow = bt * 16 + q * 4;
    const int ocol = ot * 16 + r;
#pragma unroll
    for (int reg = 0; reg < 4; ++reg)
        out[(orow + reg) * 256 + ocol] = acc[reg] * scale;
}

extern "C" void kernel_launch(void* const* d_in, const int* in_sizes, int n_in,
                              void* d_out, int out_size, void* d_ws, size_t ws_size,
                              hipStream_t stream) {
    const float* x       = (const float*)d_in[0];
    const float* grid    = (const float*)d_in[1];
    const float* c_basis = (const float*)d_in[2];
    const float* c_spl   = (const float*)d_in[3];
    const float* c_res   = (const float*)d_in[4];
    float* out = (float*)d_out;

    unsigned short* F = (unsigned short*)d_ws;                       // 512*896*2 B
    unsigned short* W = (unsigned short*)((char*)d_ws + 512 * 896 * 2);  // 256*896*2 B

    // 512*128 feature threads + 32768 weight threads = 98304 = 384 * 256
    build_fw<<<384, 256, 0, stream>>>(x, grid, c_basis, c_spl, c_res, F, W);
    // 512 tiles of 16x16, one wave each
    kan_gemm<<<512, 64, 0, stream>>>(F, W, out);
}